// Round 1
// baseline (286.069 us; speedup 1.0000x reference)
//
#include <hip/hip_runtime.h>

// CrossEntropy + per-class focal loss, MI355X (gfx950).
// logits: [8, 19, 512, 512] f32, targets: [8, 512, 512] int32, out: scalar f32.
//
// Memory-bound streaming reduction: each logit read once (float4, coalesced),
// softmax/logsumexp over the 19-class axis held entirely in registers.

#define NCLS 19
#define IGNORE_IDX 255
#define HW 262144          // 512*512
#define HW4 65536          // HW/4 (float4 groups per image per class)
#define FOCAL_EPS 1e-6f

struct Ws {
    double sum_nll;        // sum of NLL over valid pixels
    double n_valid;        // count of valid pixels
    double csum[NCLS];     // per-class focal-term sums
    double ccnt[NCLS];     // per-class valid counts
};

__global__ __launch_bounds__(256) void focal_main(
        const float* __restrict__ logits,
        const int*   __restrict__ targets,
        Ws* __restrict__ ws) {
    __shared__ float    s_csum[NCLS];
    __shared__ unsigned s_ccnt[NCLS];
    __shared__ float    s_wnll[4];
    __shared__ int      s_wcnt[4];

    const int tid = threadIdx.x;
    if (tid < NCLS) { s_csum[tid] = 0.0f; s_ccnt[tid] = 0u; }
    __syncthreads();

    // g in [0, 524288): one float4-group of 4 consecutive pixels.
    const unsigned g = blockIdx.x * 256u + tid;
    const unsigned b = g >> 16;          // image index (65536 groups/image)
    const unsigned q = g & 65535u;       // group index within image
    const float4* base = reinterpret_cast<const float4*>(logits)
                         + (size_t)b * (NCLS * (size_t)HW4) + q;

    // Stage all 19 classes x 4 pixels in registers (static indices only).
    float xs[NCLS][4];
#pragma unroll
    for (int c = 0; c < NCLS; ++c) {
        float4 v = base[(size_t)c * HW4];
        xs[c][0] = v.x; xs[c][1] = v.y; xs[c][2] = v.z; xs[c][3] = v.w;
    }

    const int4 t4 = reinterpret_cast<const int4*>(targets)[g];
    int tt[4] = { t4.x, t4.y, t4.z, t4.w };

    float nll_acc = 0.0f;
    int   vcnt    = 0;
    float fterm[4];
    int   fcls[4];
    bool  fval[4];

#pragma unroll
    for (int j = 0; j < 4; ++j) {
        const int t  = tt[j];
        const int tc = min(max(t, 0), NCLS - 1);   // reference's clip
        const bool valid = (t != IGNORE_IDX);

        float m = xs[0][j];
#pragma unroll
        for (int c = 1; c < NCLS; ++c) m = fmaxf(m, xs[c][j]);

        float s  = 0.0f;
        float xt = xs[0][j];
#pragma unroll
        for (int c = 0; c < NCLS; ++c) {
            s += __expf(xs[c][j] - m);
            if (c == tc) xt = xs[c][j];            // predicated select, no scratch
        }
        const float lse = m + __logf(s);
        const float nll = lse - xt;

        // focal: pt = clip(exp(-nll), 1e-6, 1); term = -log(pt)*(1-pt)^3
        float pt = __expf(-nll);
        pt = fminf(fmaxf(pt, FOCAL_EPS), 1.0f);
        const float om = 1.0f - pt;
        const float f  = -__logf(pt) * om * om * om;

        if (valid) { nll_acc += nll; ++vcnt; }
        fterm[j] = f; fcls[j] = tc; fval[j] = valid;
    }

    // Per-class accumulation via LDS atomics (19 slots, light contention).
#pragma unroll
    for (int j = 0; j < 4; ++j) {
        if (fval[j]) {
            atomicAdd(&s_csum[fcls[j]], fterm[j]);
            atomicAdd(&s_ccnt[fcls[j]], 1u);
        }
    }

    // Wave-64 butterfly reduce of nll/count, then per-block global atomic.
#pragma unroll
    for (int off = 32; off > 0; off >>= 1) {
        nll_acc += __shfl_down(nll_acc, off);
        vcnt    += __shfl_down(vcnt, off);
    }
    const int wid = tid >> 6, lane = tid & 63;
    if (lane == 0) { s_wnll[wid] = nll_acc; s_wcnt[wid] = vcnt; }
    __syncthreads();

    if (tid == 0) {
        float bn = s_wnll[0] + s_wnll[1] + s_wnll[2] + s_wnll[3];
        int   bc = s_wcnt[0] + s_wcnt[1] + s_wcnt[2] + s_wcnt[3];
        atomicAdd(&ws->sum_nll, (double)bn);
        atomicAdd(&ws->n_valid, (double)bc);
    }
    if (tid < NCLS) {
        atomicAdd(&ws->csum[tid], (double)s_csum[tid]);
        atomicAdd(&ws->ccnt[tid], (double)s_ccnt[tid]);
    }
}

__global__ void focal_final(const Ws* __restrict__ ws, float* __restrict__ out) {
    if (threadIdx.x == 0) {
        double nv = ws->n_valid;
        if (nv < 1.0) nv = 1.0;
        const double ce = ws->sum_nll / nv;

        double fsum = 0.0, npres = 0.0;
        for (int c = 0; c < NCLS; ++c) {
            const double cnt = ws->ccnt[c];
            if (cnt > 0.0) {
                fsum += ws->csum[c] / (cnt < 1.0 ? 1.0 : cnt);
                npres += 1.0;
            }
        }
        if (npres < 1.0) npres = 1.0;
        out[0] = (float)(ce + fsum / npres);
    }
}

extern "C" void kernel_launch(void* const* d_in, const int* in_sizes, int n_in,
                              void* d_out, int out_size, void* d_ws, size_t ws_size,
                              hipStream_t stream) {
    const float* logits  = (const float*)d_in[0];
    const int*   targets = (const int*)d_in[1];
    float*       out     = (float*)d_out;
    Ws*          ws      = (Ws*)d_ws;

    hipMemsetAsync(d_ws, 0, sizeof(Ws), stream);
    // 2048 blocks x 256 threads x 4 pixels = 2,097,152 pixels exactly.
    focal_main<<<2048, 256, 0, stream>>>(logits, targets, ws);
    focal_final<<<1, 64, 0, stream>>>(ws, out);
}

// Round 2
// 238.003 us; speedup vs baseline: 1.2020x; 1.2020x over previous
//
#include <hip/hip_runtime.h>

// CrossEntropy + per-class focal loss, MI355X (gfx950).
// logits: [8, 19, 512, 512] f32, targets: [8, 512, 512] int32, out: scalar f32.
//
// R1 lesson: 82K same-line global f64 atomics serialized at TCC (~120us).
// R2: per-block partials -> d_ws (no atomics), second kernel reduces.

#define NCLS 19
#define IGNORE_IDX 255
#define HW4 65536          // 512*512/4 (float4 groups per image per class)
#define FOCAL_EPS 1e-6f
#define NBLK 2048
#define NQ 40              // 0=nll_sum, 1=valid_cnt, 2..20=csum[c], 21..39=ccnt[c]

__global__ __launch_bounds__(256) void focal_main(
        const float* __restrict__ logits,
        const int*   __restrict__ targets,
        double* __restrict__ P) {            // P[q*NBLK + blockIdx]
    __shared__ float    s_csum[NCLS];
    __shared__ unsigned s_ccnt[NCLS];
    __shared__ float    s_wnll[4];
    __shared__ int      s_wcnt[4];

    const int tid = threadIdx.x;
    if (tid < NCLS) { s_csum[tid] = 0.0f; s_ccnt[tid] = 0u; }
    __syncthreads();

    // g in [0, 524288): one float4-group of 4 consecutive pixels.
    const unsigned g = blockIdx.x * 256u + tid;
    const unsigned b = g >> 16;          // image index (65536 groups/image)
    const unsigned q = g & 65535u;       // group index within image
    const float4* base = reinterpret_cast<const float4*>(logits)
                         + (size_t)b * (NCLS * (size_t)HW4) + q;

    // Stage all 19 classes x 4 pixels in registers (static indices only).
    float xs[NCLS][4];
#pragma unroll
    for (int c = 0; c < NCLS; ++c) {
        float4 v = base[(size_t)c * HW4];
        xs[c][0] = v.x; xs[c][1] = v.y; xs[c][2] = v.z; xs[c][3] = v.w;
    }

    const int4 t4 = reinterpret_cast<const int4*>(targets)[g];
    int tt[4] = { t4.x, t4.y, t4.z, t4.w };

    float nll_acc = 0.0f;
    int   vcnt    = 0;
    float fterm[4];
    int   fcls[4];
    bool  fval[4];

#pragma unroll
    for (int j = 0; j < 4; ++j) {
        const int t  = tt[j];
        const int tc = min(max(t, 0), NCLS - 1);   // reference's clip
        const bool valid = (t != IGNORE_IDX);

        float m = xs[0][j];
#pragma unroll
        for (int c = 1; c < NCLS; ++c) m = fmaxf(m, xs[c][j]);

        float s  = 0.0f;
        float xt = xs[0][j];
#pragma unroll
        for (int c = 0; c < NCLS; ++c) {
            s += __expf(xs[c][j] - m);
            if (c == tc) xt = xs[c][j];            // predicated select, no scratch
        }
        const float lse = m + __logf(s);
        const float nll = lse - xt;

        // focal: pt = clip(exp(-nll), 1e-6, 1); term = -log(pt)*(1-pt)^3
        float pt = __expf(-nll);
        pt = fminf(fmaxf(pt, FOCAL_EPS), 1.0f);
        const float om = 1.0f - pt;
        const float f  = -__logf(pt) * om * om * om;

        if (valid) { nll_acc += nll; ++vcnt; }
        fterm[j] = f; fcls[j] = tc; fval[j] = valid;
    }

    // Per-class accumulation via LDS atomics (19 slots, light contention).
#pragma unroll
    for (int j = 0; j < 4; ++j) {
        if (fval[j]) {
            atomicAdd(&s_csum[fcls[j]], fterm[j]);
            atomicAdd(&s_ccnt[fcls[j]], 1u);
        }
    }

    // Wave-64 butterfly reduce of nll/count, then per-block partial stores.
#pragma unroll
    for (int off = 32; off > 0; off >>= 1) {
        nll_acc += __shfl_down(nll_acc, off);
        vcnt    += __shfl_down(vcnt, off);
    }
    const int wid = tid >> 6, lane = tid & 63;
    if (lane == 0) { s_wnll[wid] = nll_acc; s_wcnt[wid] = vcnt; }
    __syncthreads();

    const unsigned bid = blockIdx.x;
    if (tid == 0) {
        float bn = s_wnll[0] + s_wnll[1] + s_wnll[2] + s_wnll[3];
        int   bc = s_wcnt[0] + s_wcnt[1] + s_wcnt[2] + s_wcnt[3];
        P[0 * NBLK + bid] = (double)bn;
        P[1 * NBLK + bid] = (double)bc;
    }
    if (tid < NCLS) {
        P[(2 + tid) * NBLK + bid]        = (double)s_csum[tid];
        P[(2 + NCLS + tid) * NBLK + bid] = (double)s_ccnt[tid];
    }
}

// One block, 1024 threads = 16 waves. Wave w reduces quantities q = w, w+16, ...
__global__ __launch_bounds__(1024) void focal_final(
        const double* __restrict__ P, float* __restrict__ out) {
    __shared__ double s_q[NQ];
    const int tid  = threadIdx.x;
    const int wid  = tid >> 6;
    const int lane = tid & 63;

    for (int q = wid; q < NQ; q += 16) {
        double v = 0.0;
#pragma unroll
        for (int k = 0; k < NBLK / 64; ++k)
            v += P[q * NBLK + lane + 64 * k];
#pragma unroll
        for (int off = 32; off > 0; off >>= 1)
            v += __shfl_down(v, off);
        if (lane == 0) s_q[q] = v;
    }
    __syncthreads();

    if (tid == 0) {
        double nv = s_q[1];
        if (nv < 1.0) nv = 1.0;
        const double ce = s_q[0] / nv;

        double fsum = 0.0, npres = 0.0;
        for (int c = 0; c < NCLS; ++c) {
            const double cnt = s_q[2 + NCLS + c];
            if (cnt > 0.0) {
                fsum += s_q[2 + c] / (cnt < 1.0 ? 1.0 : cnt);
                npres += 1.0;
            }
        }
        if (npres < 1.0) npres = 1.0;
        out[0] = (float)(ce + fsum / npres);
    }
}

extern "C" void kernel_launch(void* const* d_in, const int* in_sizes, int n_in,
                              void* d_out, int out_size, void* d_ws, size_t ws_size,
                              hipStream_t stream) {
    const float* logits  = (const float*)d_in[0];
    const int*   targets = (const int*)d_in[1];
    float*       out     = (float*)d_out;
    double*      P       = (double*)d_ws;   // NQ * NBLK doubles = 656 KB

    // 2048 blocks x 256 threads x 4 pixels = 2,097,152 pixels exactly.
    focal_main<<<NBLK, 256, 0, stream>>>(logits, targets, P);
    focal_final<<<1, 1024, 0, stream>>>(P, out);
}